// Round 11
// baseline (296.520 us; speedup 1.0000x reference)
//
#include <hip/hip_runtime.h>
#include <hip/hip_bf16.h>
#include <math.h>

// Problem: B=2, S=2048, D=1024, H=16, dk=64.  Inputs/outputs fp32; internal compute bf16 MFMA.
// d_out = [ out: 4096x1024 f32 | attn_weights: 32 x 2048 x 2048 f32 ]
// d_ws (fast path, 64 MB): [ q | k | vT | attn_out | Qb | Kb | Vb | Wqb | Wkb | Wvb | Wob ] bf16
// q workspace is PRE-SCALED by (1/8)*log2(e) so attn uses exp2(sj) directly.
// Config: QKV = gemm_bb, out-proj = gemm_n64<0>, attn = QBLK=128 (this round's single change).

typedef __bf16 bf16;
typedef __bf16 bf16x8 __attribute__((ext_vector_type(8)));
typedef float  f32x4  __attribute__((ext_vector_type(4)));

#define GLDS16(gp, lp) __builtin_amdgcn_global_load_lds(                     \
    (const __attribute__((address_space(1))) void*)(gp),                     \
    (__attribute__((address_space(3))) void*)(lp), 16, 0, 0)

#define QSCALE 0.18033688011112042f   // (1/8) * log2(e)

static __device__ __forceinline__ bf16x8 cvt8(const f32x4 lo, const f32x4 hi) {
    bf16x8 r;
    r[0] = (bf16)lo[0]; r[1] = (bf16)lo[1]; r[2] = (bf16)lo[2]; r[3] = (bf16)lo[3];
    r[4] = (bf16)hi[0]; r[5] = (bf16)hi[1]; r[6] = (bf16)hi[2]; r[7] = (bf16)hi[3];
    return r;
}

// ---------------------------------------------------------------------------
// Prologue: fp32 -> bf16 for Q,K,V and Wq,Wk,Wv,Wo.  (unchanged)
// ---------------------------------------------------------------------------
__global__ __launch_bounds__(256)
void cvt7(const float* __restrict__ s0, const float* __restrict__ s1, const float* __restrict__ s2,
          const float* __restrict__ s3, const float* __restrict__ s4, const float* __restrict__ s5,
          const float* __restrict__ s6,
          bf16* __restrict__ d0, bf16* __restrict__ d1, bf16* __restrict__ d2,
          bf16* __restrict__ d3, bf16* __restrict__ d4, bf16* __restrict__ d5,
          bf16* __restrict__ d6)
{
    const int seg = blockIdx.y;
    const float* s; bf16* d; int n;
    switch (seg) {
        case 0: s = s0; d = d0; n = 4194304; break;
        case 1: s = s1; d = d1; n = 4194304; break;
        case 2: s = s2; d = d2; n = 4194304; break;
        case 3: s = s3; d = d3; n = 1048576; break;
        case 4: s = s4; d = d4; n = 1048576; break;
        case 5: s = s5; d = d5; n = 1048576; break;
        default: s = s6; d = d6; n = 1048576; break;
    }
    const size_t i = ((size_t)blockIdx.x * 256 + threadIdx.x) * 8;
    if (i >= (size_t)n) return;
    const f32x4 lo = *(const f32x4*)(s + i);
    const f32x4 hi = *(const f32x4*)(s + i + 4);
    *(bf16x8*)(d + i) = cvt8(lo, hi);
}

// ---------------------------------------------------------------------------
// Pure-bf16 GEMM, 128x128 tile (m97 structure) — used for QKV.  (unchanged)
// ---------------------------------------------------------------------------
template<int MODE>
__global__ __launch_bounds__(256)
void gemm_bb(const bf16* __restrict__ A0, const bf16* __restrict__ A1, const bf16* __restrict__ A2,
             const bf16* __restrict__ W0, const bf16* __restrict__ W1, const bf16* __restrict__ W2,
             const float* __restrict__ B0, const float* __restrict__ B1, const float* __restrict__ B2,
             void* __restrict__ O0v, void* __restrict__ O1v, void* __restrict__ O2v)
{
    __shared__ __align__(16) bf16 As[128 * 32];
    __shared__ __align__(16) bf16 Bs[128 * 32];

    const int tid  = threadIdx.x;
    const int lane = tid & 63;
    const int w    = tid >> 6;
    const int wr   = w >> 1, wc = w & 1;
    const int g    = lane >> 4, c = lane & 15;

    const int mb  = blockIdx.x, nb = blockIdx.y;
    const int mat = (MODE == 1) ? (nb >> 3) : 0;
    const int nbi = (MODE == 1) ? (nb & 7) : nb;

    const bf16*  A  = (MODE == 1) ? (mat == 0 ? A0 : (mat == 1 ? A1 : A2)) : A0;
    const bf16*  W  = (MODE == 1) ? (mat == 0 ? W0 : (mat == 1 ? W1 : W2)) : W0;
    const float* Bi = (MODE == 1) ? (mat == 0 ? B0 : (mat == 1 ? B1 : B2)) : B0;

    const size_t m0 = (size_t)mb * 128;
    const int    n0 = nbi * 128;

    f32x4 acc[4][4];
#pragma unroll
    for (int i = 0; i < 4; i++)
#pragma unroll
        for (int j = 0; j < 4; j++) acc[i][j] = (f32x4){0.f, 0.f, 0.f, 0.f};

    const int srow = lane >> 2;
    const int spos = lane & 3;

    for (int k0 = 0; k0 < 1024; k0 += 32) {
        __syncthreads();
#pragma unroll
        for (int s = 0; s < 2; s++) {
            const int ca  = w * 2 + s;
            const int row = ca * 16 + srow;
            GLDS16(A + (size_t)(m0 + row) * 1024 + k0 + ((spos ^ ((row >> 1) & 3)) << 3),
                   &As[ca * 512]);
            GLDS16(W + (size_t)(n0 + row) * 1024 + k0 + ((spos ^ ((row >> 1) & 3)) << 3),
                   &Bs[ca * 512]);
        }
        __syncthreads();

        bf16x8 av[4], bv[4];
#pragma unroll
        for (int i = 0; i < 4; i++) {
            const int row = wr * 64 + i * 16 + c;
            av[i] = *(const bf16x8*)&As[row * 32 + ((g ^ ((row >> 1) & 3)) << 3)];
        }
#pragma unroll
        for (int j = 0; j < 4; j++) {
            const int row = wc * 64 + j * 16 + c;
            bv[j] = *(const bf16x8*)&Bs[row * 32 + ((g ^ ((row >> 1) & 3)) << 3)];
        }
#pragma unroll
        for (int i = 0; i < 4; i++)
#pragma unroll
            for (int j = 0; j < 4; j++)
                acc[i][j] = __builtin_amdgcn_mfma_f32_16x16x32_bf16(av[i], bv[j], acc[i][j], 0, 0, 0);
    }

    const float scl = (MODE == 1 && mat == 0) ? QSCALE : 1.0f;
#pragma unroll
    for (int j = 0; j < 4; j++) {
        const int   nl   = wc * 64 + j * 16 + c;
        const int   n    = n0 + nl;
        const float bval = Bi[n];
#pragma unroll
        for (int i = 0; i < 4; i++) {
#pragma unroll
            for (int r = 0; r < 4; r++) {
                const size_t m   = m0 + wr * 64 + i * 16 + g * 4 + r;
                const float  val = (acc[i][j][r] + bval) * scl;
                if (MODE == 0) {
                    ((float*)O0v)[m * 1024 + n] = val;
                } else {
                    const bf16 ob = (bf16)val;
                    const int  bb = (int)(m >> 11), s = (int)(m & 2047);
                    const int  hh = n >> 6, d = n & 63;
                    if (mat < 2) {
                        bf16* Oqk = (mat == 0) ? (bf16*)O0v : (bf16*)O1v;
                        Oqk[(((size_t)bb * 16 + hh) * 2048 + s) * 64 + d] = ob;
                    } else {
                        ((bf16*)O2v)[(((size_t)bb * 16 + hh) * 64 + d) * 2048 + s] = ob;  // vT
                    }
                }
            }
        }
    }
}

// ---------------------------------------------------------------------------
// GEMM n64: BM=128, BN=64 — OUT-PROJ (512 blocks = 2/CU).  (unchanged)
// ---------------------------------------------------------------------------
template<int MODE>
__global__ __launch_bounds__(256)
void gemm_n64(const bf16* __restrict__ A0, const bf16* __restrict__ W0,
              const float* __restrict__ B0, void* __restrict__ O0v)
{
    __shared__ __align__(16) bf16 As[128 * 32];
    __shared__ __align__(16) bf16 Bs[64 * 32];

    const int tid  = threadIdx.x;
    const int lane = tid & 63;
    const int w    = tid >> 6;
    const int wr   = w >> 1, wc = w & 1;
    const int g    = lane >> 4, c = lane & 15;

    const int mb = blockIdx.x, nbi = blockIdx.y;

    const size_t m0 = (size_t)mb * 128;
    const int    n0 = nbi * 64;

    f32x4 acc[4][2];
#pragma unroll
    for (int i = 0; i < 4; i++)
#pragma unroll
        for (int j = 0; j < 2; j++) acc[i][j] = (f32x4){0.f, 0.f, 0.f, 0.f};

    const int srow = lane >> 2;
    const int spos = lane & 3;

    for (int k0 = 0; k0 < 1024; k0 += 32) {
        __syncthreads();
#pragma unroll
        for (int s = 0; s < 2; s++) {
            const int ca  = w * 2 + s;
            const int row = ca * 16 + srow;
            GLDS16(A0 + (size_t)(m0 + row) * 1024 + k0 + ((spos ^ ((row >> 1) & 3)) << 3),
                   &As[ca * 512]);
        }
        {
            const int row = w * 16 + srow;
            GLDS16(W0 + (size_t)(n0 + row) * 1024 + k0 + ((spos ^ ((row >> 1) & 3)) << 3),
                   &Bs[w * 512]);
        }
        __syncthreads();

        bf16x8 av[4], bv[2];
#pragma unroll
        for (int i = 0; i < 4; i++) {
            const int row = wr * 64 + i * 16 + c;
            av[i] = *(const bf16x8*)&As[row * 32 + ((g ^ ((row >> 1) & 3)) << 3)];
        }
#pragma unroll
        for (int j = 0; j < 2; j++) {
            const int row = wc * 32 + j * 16 + c;
            bv[j] = *(const bf16x8*)&Bs[row * 32 + ((g ^ ((row >> 1) & 3)) << 3)];
        }
#pragma unroll
        for (int i = 0; i < 4; i++)
#pragma unroll
            for (int j = 0; j < 2; j++)
                acc[i][j] = __builtin_amdgcn_mfma_f32_16x16x32_bf16(av[i], bv[j], acc[i][j], 0, 0, 0);
    }

#pragma unroll
    for (int j = 0; j < 2; j++) {
        const int   nl   = wc * 32 + j * 16 + c;
        const int   n    = n0 + nl;
        const float bval = B0[n];
#pragma unroll
        for (int i = 0; i < 4; i++) {
#pragma unroll
            for (int r = 0; r < 4; r++) {
                const size_t m = m0 + wr * 64 + i * 16 + g * 4 + r;
                ((float*)O0v)[m * 1024 + n] = acc[i][j][r] + bval;
            }
        }
    }
}

// ---------------------------------------------------------------------------
// Fallback GEMM (fp32 staging) — used only if ws_size < 64 MB.  (unchanged)
// ---------------------------------------------------------------------------
template<int MODE>
__global__ __launch_bounds__(256)
void gemm_bt(const void* __restrict__ A0v, const void* __restrict__ A1v, const void* __restrict__ A2v,
             const float* __restrict__ W0, const float* __restrict__ W1, const float* __restrict__ W2,
             const float* __restrict__ B0, const float* __restrict__ B1, const float* __restrict__ B2,
             void* __restrict__ O0v, void* __restrict__ O1v, void* __restrict__ O2v)
{
    __shared__ __align__(16) float AsF[128 * 32];
    __shared__ __align__(16) float BsF[128 * 32];
    bf16* AsH = (bf16*)AsF;

    const int tid  = threadIdx.x;
    const int lane = tid & 63;
    const int w    = tid >> 6;
    const int wr   = w >> 1, wc = w & 1;
    const int g    = lane >> 4, c = lane & 15;

    const int mb  = blockIdx.x, nb = blockIdx.y;
    const int mat = (MODE == 1) ? (nb >> 3) : 0;
    const int nbi = (MODE == 1) ? (nb & 7) : nb;

    const float* Af = (MODE == 1)
        ? (mat == 0 ? (const float*)A0v : (mat == 1 ? (const float*)A1v : (const float*)A2v))
        : nullptr;
    const bf16*  Ah = (MODE == 0) ? (const bf16*)A0v : nullptr;
    const float* W  = (MODE == 1) ? (mat == 0 ? W0 : (mat == 1 ? W1 : W2)) : W0;
    const float* Bi = (MODE == 1) ? (mat == 0 ? B0 : (mat == 1 ? B1 : B2)) : B0;

    const size_t m0 = (size_t)mb * 128;
    const int    n0 = nbi * 128;

    f32x4 acc[4][4];
#pragma unroll
    for (int i = 0; i < 4; i++)
#pragma unroll
        for (int j = 0; j < 4; j++) acc[i][j] = (f32x4){0.f, 0.f, 0.f, 0.f};

    for (int k0 = 0; k0 < 1024; k0 += 32) {
        __syncthreads();
        if constexpr (MODE == 1) {
#pragma unroll
            for (int s = 0; s < 4; s++) {
                const int ca  = w * 4 + s;
                const int row = ca * 8 + (lane >> 3);
                const int pos = lane & 7;
                GLDS16(Af + (size_t)(m0 + row) * 1024 + k0 + ((pos ^ (row & 7)) << 2), &AsF[ca * 256]);
            }
        } else {
#pragma unroll
            for (int s = 0; s < 2; s++) {
                const int ca  = w * 2 + s;
                const int row = ca * 16 + (lane >> 2);
                const int pos = lane & 3;
                GLDS16(Ah + (size_t)(m0 + row) * 1024 + k0 + ((pos ^ ((row >> 1) & 3)) << 3), &AsH[ca * 512]);
            }
        }
#pragma unroll
        for (int s = 0; s < 4; s++) {
            const int cb  = w * 4 + s;
            const int row = cb * 8 + (lane >> 3);
            const int pos = lane & 7;
            GLDS16(W + (size_t)(n0 + row) * 1024 + k0 + ((pos ^ (row & 7)) << 2), &BsF[cb * 256]);
        }
        __syncthreads();

        bf16x8 av[4], bv[4];
#pragma unroll
        for (int i = 0; i < 4; i++) {
            const int row = wr * 64 + i * 16 + c;
            if constexpr (MODE == 1) {
                const int s7 = row & 7;
                const f32x4 lo = *(const f32x4*)&AsF[row * 32 + (((2 * g)     ^ s7) << 2)];
                const f32x4 hi = *(const f32x4*)&AsF[row * 32 + (((2 * g + 1) ^ s7) << 2)];
                av[i] = cvt8(lo, hi);
            } else {
                av[i] = *(const bf16x8*)&AsH[row * 32 + ((g ^ ((row >> 1) & 3)) << 3)];
            }
        }
#pragma unroll
        for (int j = 0; j < 4; j++) {
            const int row = wc * 64 + j * 16 + c;
            const int s7  = row & 7;
            const f32x4 lo = *(const f32x4*)&BsF[row * 32 + (((2 * g)     ^ s7) << 2)];
            const f32x4 hi = *(const f32x4*)&BsF[row * 32 + (((2 * g + 1) ^ s7) << 2)];
            bv[j] = cvt8(lo, hi);
        }
#pragma unroll
        for (int i = 0; i < 4; i++)
#pragma unroll
            for (int j = 0; j < 4; j++)
                acc[i][j] = __builtin_amdgcn_mfma_f32_16x16x32_bf16(av[i], bv[j], acc[i][j], 0, 0, 0);
    }

    const float scl = (MODE == 1 && mat == 0) ? QSCALE : 1.0f;
#pragma unroll
    for (int j = 0; j < 4; j++) {
        const int   nl   = wc * 64 + j * 16 + c;
        const int   n    = n0 + nl;
        const float bval = Bi[n];
#pragma unroll
        for (int i = 0; i < 4; i++) {
#pragma unroll
            for (int r = 0; r < 4; r++) {
                const size_t m   = m0 + wr * 64 + i * 16 + g * 4 + r;
                const float  val = (acc[i][j][r] + bval) * scl;
                if (MODE == 0) {
                    ((float*)O0v)[m * 1024 + n] = val;
                } else {
                    const bf16 ob = (bf16)val;
                    const int  bb = (int)(m >> 11), s = (int)(m & 2047);
                    const int  hh = n >> 6, d = n & 63;
                    if (mat < 2) {
                        bf16* Oqk = (mat == 0) ? (bf16*)O0v : (bf16*)O1v;
                        Oqk[(((size_t)bb * 16 + hh) * 2048 + s) * 64 + d] = ob;
                    } else {
                        ((bf16*)O2v)[(((size_t)bb * 16 + hh) * 64 + d) * 2048 + s] = ob;  // vT
                    }
                }
            }
        }
    }
}

// ---------------------------------------------------------------------------
// Attention v6: QBLK=128 (wave owns 32 q-rows = 2 row-groups).  Same R6 pipe
// shape (dbuf K/V, scalar nt stores inside exp2 loop, counted end-of-tile
// vmcnt), but 2x compute per barrier, half the blocks (512), half the K/V
// read pressure.  LDS = 16K(K) + 16K(V) + 16K(Ps) = 48 KB -> 3 blocks/CU.
// ---------------------------------------------------------------------------
__global__ __launch_bounds__(256, 3)
void attn_kernel(const bf16* __restrict__ Qh, const bf16* __restrict__ Kh,
                 const bf16* __restrict__ VhT, float* __restrict__ PW,
                 bf16* __restrict__ AO)
{
    __shared__ __align__(16) bf16 Ks[2 * 64 * 64];
    __shared__ __align__(16) bf16 Vs[2 * 64 * 64];
    __shared__ __align__(16) bf16 Ps[128 * 64];

    const int tid  = threadIdx.x;
    const int lane = tid & 63;
    const int w    = tid >> 6;
    const int g    = lane >> 4, c = lane & 15;

    const int L   = blockIdx.x;                 // 0..511
    const int swz = (L & 7) * 64 + (L >> 3);    // bijective (512 = 8*64)
    const int bh  = swz >> 4;                   // 0..31
    const int qb  = swz & 15;                   // 0..15 (128-row q tiles)

    const bf16* qp = Qh + (((size_t)bh * 2048) + qb * 128) * 64;
    const bf16* kp = Kh + ((size_t)bh * 2048) * 64;
    const bf16* vp = VhT + ((size_t)bh * 64) * 2048;
    float*      pw = PW + (size_t)bh * 2048 * 2048 + (size_t)(qb * 128) * 2048;

    // q fragments: row-group rg covers rows w*32 + rg*16 + c
    bf16x8 aq[2][2];
#pragma unroll
    for (int rg = 0; rg < 2; rg++)
#pragma unroll
        for (int kk = 0; kk < 2; kk++)
            aq[rg][kk] = *(const bf16x8*)(qp + (w * 32 + rg * 16 + c) * 64 + kk * 32 + g * 8);

    const int srow = (lane >> 3);
    const int spos = lane & 7;

    // ---- PASS A ----
    float lr[2][4] = {{0.f,0.f,0.f,0.f},{0.f,0.f,0.f,0.f}};
#pragma unroll
    for (int s2 = 0; s2 < 2; s2++) {
        const int cs = w * 2 + s2, row = cs * 8 + srow;
        GLDS16(kp + (size_t)row * 64 + ((spos ^ (row & 7)) << 3), &Ks[cs * 512]);
    }
    asm volatile("s_waitcnt vmcnt(0)" ::: "memory");
    __builtin_amdgcn_s_barrier();
    asm volatile("" ::: "memory");

    for (int t = 0; t < 32; t++) {
        const bf16* kb = &Ks[(t & 1) * 4096];
        if (t < 31) {
#pragma unroll
            for (int s2 = 0; s2 < 2; s2++) {
                const int cs = w * 2 + s2, row = cs * 8 + srow;
                GLDS16(kp + (size_t)((t + 1) * 64 + row) * 64 + ((spos ^ (row & 7)) << 3),
                       &Ks[((t + 1) & 1) * 4096 + cs * 512]);
            }
        }
        f32x4 sj[2][4];
#pragma unroll
        for (int rg = 0; rg < 2; rg++)
#pragma unroll
            for (int j = 0; j < 4; j++) sj[rg][j] = (f32x4){0.f, 0.f, 0.f, 0.f};
#pragma unroll
        for (int kk = 0; kk < 2; kk++) {
#pragma unroll
            for (int j = 0; j < 4; j++) {
                const int row = j * 16 + c;
                const bf16x8 bk = *(const bf16x8*)&kb[row * 64 + (((kk * 4 + g) ^ (row & 7)) << 3)];
                sj[0][j] = __builtin_amdgcn_mfma_f32_16x16x32_bf16(aq[0][kk], bk, sj[0][j], 0, 0, 0);
                sj[1][j] = __builtin_amdgcn_mfma_f32_16x16x32_bf16(aq[1][kk], bk, sj[1][j], 0, 0, 0);
            }
        }
#pragma unroll
        for (int rg = 0; rg < 2; rg++)
#pragma unroll
            for (int r = 0; r < 4; r++)
                lr[rg][r] += exp2f(sj[rg][0][r]) + exp2f(sj[rg][1][r])
                           + exp2f(sj[rg][2][r]) + exp2f(sj[rg][3][r]);

        asm volatile("s_waitcnt vmcnt(0)" ::: "memory");
        __builtin_amdgcn_s_barrier();
        asm volatile("" ::: "memory");
    }

    float inv[2][4];
#pragma unroll
    for (int rg = 0; rg < 2; rg++)
#pragma unroll
        for (int r = 0; r < 4; r++) {
            float s = lr[rg][r];
            s += __shfl_xor(s, 1);
            s += __shfl_xor(s, 2);
            s += __shfl_xor(s, 4);
            s += __shfl_xor(s, 8);
            inv[rg][r] = 1.0f / s;
        }

    f32x4 oj[2][4];
#pragma unroll
    for (int rg = 0; rg < 2; rg++)
#pragma unroll
        for (int j = 0; j < 4; j++) oj[rg][j] = (f32x4){0.f, 0.f, 0.f, 0.f};

    // ---- PASS B ----
#pragma unroll
    for (int s2 = 0; s2 < 2; s2++) {
        const int cs = w * 2 + s2, row = cs * 8 + srow;
        GLDS16(kp + (size_t)row * 64 + ((spos ^ (row & 7)) << 3), &Ks[cs * 512]);
        GLDS16(vp + (size_t)row * 2048 + ((spos ^ (row & 7)) << 3), &Vs[cs * 512]);
    }
    asm volatile("s_waitcnt vmcnt(0)" ::: "memory");
    __builtin_amdgcn_s_barrier();
    asm volatile("" ::: "memory");

    for (int t = 0; t < 32; t++) {
        const bf16* kb = &Ks[(t & 1) * 4096];
        const bf16* vb = &Vs[(t & 1) * 4096];
        if (t < 31) {
#pragma unroll
            for (int s2 = 0; s2 < 2; s2++) {
                const int cs = w * 2 + s2, row = cs * 8 + srow;
                GLDS16(kp + (size_t)((t + 1) * 64 + row) * 64 + ((spos ^ (row & 7)) << 3),
                       &Ks[((t + 1) & 1) * 4096 + cs * 512]);
                GLDS16(vp + (size_t)row * 2048 + (t + 1) * 64 + ((spos ^ (row & 7)) << 3),
                       &Vs[((t + 1) & 1) * 4096 + cs * 512]);
            }
        }
        f32x4 sj[2][4];
#pragma unroll
        for (int rg = 0; rg < 2; rg++)
#pragma unroll
            for (int j = 0; j < 4; j++) sj[rg][j] = (f32x4){0.f, 0.f, 0.f, 0.f};
#pragma unroll
        for (int kk = 0; kk < 2; kk++) {
#pragma unroll
            for (int j = 0; j < 4; j++) {
                const int row = j * 16 + c;
                const bf16x8 bk = *(const bf16x8*)&kb[row * 64 + (((kk * 4 + g) ^ (row & 7)) << 3)];
                sj[0][j] = __builtin_amdgcn_mfma_f32_16x16x32_bf16(aq[0][kk], bk, sj[0][j], 0, 0, 0);
                sj[1][j] = __builtin_amdgcn_mfma_f32_16x16x32_bf16(aq[1][kk], bk, sj[1][j], 0, 0, 0);
            }
        }
        // normalized P: fp32 nontemporal from regs + bf16 to wave-private LDS
#pragma unroll
        for (int rg = 0; rg < 2; rg++) {
#pragma unroll
            for (int j = 0; j < 4; j++) {
#pragma unroll
                for (int r = 0; r < 4; r++) {
                    const float p   = exp2f(sj[rg][j][r]) * inv[rg][r];
                    const int   row = w * 32 + rg * 16 + g * 4 + r;
                    const int   col = j * 16 + c;
                    __builtin_nontemporal_store(p, &pw[(size_t)row * 2048 + t * 64 + col]);
                    Ps[row * 64 + (((col >> 3) ^ (row & 7)) << 3) + (col & 7)] = (bf16)p;
                }
            }
        }
        // O += P V  (Ps rows are this wave's own band: no barrier needed)
#pragma unroll
        for (int kk = 0; kk < 2; kk++) {
            const int p0 = w * 32 + c;
            const int p1 = w * 32 + 16 + c;
            const bf16x8 ap0 = *(const bf16x8*)&Ps[p0 * 64 + (((kk * 4 + g) ^ (p0 & 7)) << 3)];
            const bf16x8 ap1 = *(const bf16x8*)&Ps[p1 * 64 + (((kk * 4 + g) ^ (p1 & 7)) << 3)];
#pragma unroll
            for (int j = 0; j < 4; j++) {
                const int vrow = j * 16 + c;
                const bf16x8 bvv = *(const bf16x8*)&vb[vrow * 64 + (((kk * 4 + g) ^ (vrow & 7)) << 3)];
                oj[0][j] = __builtin_amdgcn_mfma_f32_16x16x32_bf16(ap0, bvv, oj[0][j], 0, 0, 0);
                oj[1][j] = __builtin_amdgcn_mfma_f32_16x16x32_bf16(ap1, bvv, oj[1][j], 0, 0, 0);
            }
        }
        // outstanding = 4 K/V loads (oldest) + 32 P stores; drain only the loads
        asm volatile("s_waitcnt vmcnt(32)" ::: "memory");
        __builtin_amdgcn_s_barrier();
        asm volatile("" ::: "memory");
    }

    const int b = bh >> 4, h = bh & 15;
#pragma unroll
    for (int rg = 0; rg < 2; rg++) {
#pragma unroll
        for (int j = 0; j < 4; j++) {
#pragma unroll
            for (int r = 0; r < 4; r++) {
                const size_t m = (size_t)b * 2048 + qb * 128 + w * 32 + rg * 16 + g * 4 + r;
                const int    n = h * 64 + j * 16 + c;
                AO[m * 1024 + n] = (bf16)oj[rg][j][r];
            }
        }
    }
}

// ---------------------------------------------------------------------------
extern "C" void kernel_launch(void* const* d_in, const int* in_sizes, int n_in,
                              void* d_out, int out_size, void* d_ws, size_t ws_size,
                              hipStream_t stream)
{
    const float* Q  = (const float*)d_in[0];
    const float* K  = (const float*)d_in[1];
    const float* V  = (const float*)d_in[2];
    const float* Wq = (const float*)d_in[3];
    const float* bq = (const float*)d_in[4];
    const float* Wk = (const float*)d_in[5];
    const float* bk = (const float*)d_in[6];
    const float* Wv = (const float*)d_in[7];
    const float* bv = (const float*)d_in[8];
    const float* Wo = (const float*)d_in[9];
    const float* bo = (const float*)d_in[10];

    float* outf  = (float*)d_out;                        // [4096][1024] f32
    float* attnw = outf + (size_t)4096 * 1024;           // [32][2048][2048] f32

    bf16* ws   = (bf16*)d_ws;
    bf16* qws  = ws;                                     // [32][2048][64] (pre-scaled)
    bf16* kws  = ws + 4194304;                           // [32][2048][64]
    bf16* vws  = ws + 8388608;                           // [32][64][2048] (transposed)
    bf16* aows = ws + 12582912;                          // [4096][1024]

    if (ws_size >= 67108864) {
        bf16* Qb  = ws + 16777216;
        bf16* Kb  = ws + 20971520;
        bf16* Vb  = ws + 25165824;
        bf16* Wqb = ws + 29360128;
        bf16* Wkb = ws + 30408704;
        bf16* Wvb = ws + 31457280;
        bf16* Wob = ws + 32505856;

        cvt7<<<dim3(2048, 7), 256, 0, stream>>>(Q, K, V, Wq, Wk, Wv, Wo,
                                                Qb, Kb, Vb, Wqb, Wkb, Wvb, Wob);
        gemm_bb<1><<<dim3(32, 24), 256, 0, stream>>>(Qb, Kb, Vb, Wqb, Wkb, Wvb,
                                                     bq, bk, bv, qws, kws, vws);
        attn_kernel<<<dim3(512), 256, 0, stream>>>(qws, kws, vws, attnw, aows);
        gemm_n64<0><<<dim3(32, 16), 256, 0, stream>>>(aows, Wob, bo, outf);
    } else {
        gemm_bt<1><<<dim3(32, 24), 256, 0, stream>>>(Q, K, V, Wq, Wk, Wv, bq, bk, bv, qws, kws, vws);
        attn_kernel<<<dim3(512), 256, 0, stream>>>(qws, kws, vws, attnw, aows);
        gemm_bt<0><<<dim3(32, 8), 256, 0, stream>>>(aows, nullptr, nullptr, Wo, nullptr, nullptr,
                                                    bo, nullptr, nullptr, outf, nullptr, nullptr);
    }
}

// Round 12
// 271.937 us; speedup vs baseline: 1.0904x; 1.0904x over previous
//
#include <hip/hip_runtime.h>
#include <hip/hip_bf16.h>
#include <math.h>

// Problem: B=2, S=2048, D=1024, H=16, dk=64.  Inputs/outputs fp32; internal compute bf16 MFMA.
// d_out = [ out: 4096x1024 f32 | attn_weights: 32 x 2048 x 2048 f32 ]
// d_ws (fast path, 64 MB): [ q | k | vT | attn_out | Qb | Kb | Vb | Wqb | Wkb | Wvb | Wob ] bf16
// q workspace is PRE-SCALED by (1/8)*log2(e) so attn uses exp2(sj) directly.
// Config: QKV = gemm_bb, out-proj = gemm_n64<0>, attn = QBLK=64 / 32KB LDS / 5 blocks/CU.

typedef __bf16 bf16;
typedef __bf16 bf16x8 __attribute__((ext_vector_type(8)));
typedef float  f32x4  __attribute__((ext_vector_type(4)));

#define GLDS16(gp, lp) __builtin_amdgcn_global_load_lds(                     \
    (const __attribute__((address_space(1))) void*)(gp),                     \
    (__attribute__((address_space(3))) void*)(lp), 16, 0, 0)

#define QSCALE 0.18033688011112042f   // (1/8) * log2(e)

static __device__ __forceinline__ bf16x8 cvt8(const f32x4 lo, const f32x4 hi) {
    bf16x8 r;
    r[0] = (bf16)lo[0]; r[1] = (bf16)lo[1]; r[2] = (bf16)lo[2]; r[3] = (bf16)lo[3];
    r[4] = (bf16)hi[0]; r[5] = (bf16)hi[1]; r[6] = (bf16)hi[2]; r[7] = (bf16)hi[3];
    return r;
}

// ---------------------------------------------------------------------------
// Prologue: fp32 -> bf16 for Q,K,V and Wq,Wk,Wv,Wo.  (unchanged)
// ---------------------------------------------------------------------------
__global__ __launch_bounds__(256)
void cvt7(const float* __restrict__ s0, const float* __restrict__ s1, const float* __restrict__ s2,
          const float* __restrict__ s3, const float* __restrict__ s4, const float* __restrict__ s5,
          const float* __restrict__ s6,
          bf16* __restrict__ d0, bf16* __restrict__ d1, bf16* __restrict__ d2,
          bf16* __restrict__ d3, bf16* __restrict__ d4, bf16* __restrict__ d5,
          bf16* __restrict__ d6)
{
    const int seg = blockIdx.y;
    const float* s; bf16* d; int n;
    switch (seg) {
        case 0: s = s0; d = d0; n = 4194304; break;
        case 1: s = s1; d = d1; n = 4194304; break;
        case 2: s = s2; d = d2; n = 4194304; break;
        case 3: s = s3; d = d3; n = 1048576; break;
        case 4: s = s4; d = d4; n = 1048576; break;
        case 5: s = s5; d = d5; n = 1048576; break;
        default: s = s6; d = d6; n = 1048576; break;
    }
    const size_t i = ((size_t)blockIdx.x * 256 + threadIdx.x) * 8;
    if (i >= (size_t)n) return;
    const f32x4 lo = *(const f32x4*)(s + i);
    const f32x4 hi = *(const f32x4*)(s + i + 4);
    *(bf16x8*)(d + i) = cvt8(lo, hi);
}

// ---------------------------------------------------------------------------
// Pure-bf16 GEMM, 128x128 tile (m97 structure) — used for QKV.  (unchanged)
// ---------------------------------------------------------------------------
template<int MODE>
__global__ __launch_bounds__(256)
void gemm_bb(const bf16* __restrict__ A0, const bf16* __restrict__ A1, const bf16* __restrict__ A2,
             const bf16* __restrict__ W0, const bf16* __restrict__ W1, const bf16* __restrict__ W2,
             const float* __restrict__ B0, const float* __restrict__ B1, const float* __restrict__ B2,
             void* __restrict__ O0v, void* __restrict__ O1v, void* __restrict__ O2v)
{
    __shared__ __align__(16) bf16 As[128 * 32];
    __shared__ __align__(16) bf16 Bs[128 * 32];

    const int tid  = threadIdx.x;
    const int lane = tid & 63;
    const int w    = tid >> 6;
    const int wr   = w >> 1, wc = w & 1;
    const int g    = lane >> 4, c = lane & 15;

    const int mb  = blockIdx.x, nb = blockIdx.y;
    const int mat = (MODE == 1) ? (nb >> 3) : 0;
    const int nbi = (MODE == 1) ? (nb & 7) : nb;

    const bf16*  A  = (MODE == 1) ? (mat == 0 ? A0 : (mat == 1 ? A1 : A2)) : A0;
    const bf16*  W  = (MODE == 1) ? (mat == 0 ? W0 : (mat == 1 ? W1 : W2)) : W0;
    const float* Bi = (MODE == 1) ? (mat == 0 ? B0 : (mat == 1 ? B1 : B2)) : B0;

    const size_t m0 = (size_t)mb * 128;
    const int    n0 = nbi * 128;

    f32x4 acc[4][4];
#pragma unroll
    for (int i = 0; i < 4; i++)
#pragma unroll
        for (int j = 0; j < 4; j++) acc[i][j] = (f32x4){0.f, 0.f, 0.f, 0.f};

    const int srow = lane >> 2;
    const int spos = lane & 3;

    for (int k0 = 0; k0 < 1024; k0 += 32) {
        __syncthreads();
#pragma unroll
        for (int s = 0; s < 2; s++) {
            const int ca  = w * 2 + s;
            const int row = ca * 16 + srow;
            GLDS16(A + (size_t)(m0 + row) * 1024 + k0 + ((spos ^ ((row >> 1) & 3)) << 3),
                   &As[ca * 512]);
            GLDS16(W + (size_t)(n0 + row) * 1024 + k0 + ((spos ^ ((row >> 1) & 3)) << 3),
                   &Bs[ca * 512]);
        }
        __syncthreads();

        bf16x8 av[4], bv[4];
#pragma unroll
        for (int i = 0; i < 4; i++) {
            const int row = wr * 64 + i * 16 + c;
            av[i] = *(const bf16x8*)&As[row * 32 + ((g ^ ((row >> 1) & 3)) << 3)];
        }
#pragma unroll
        for (int j = 0; j < 4; j++) {
            const int row = wc * 64 + j * 16 + c;
            bv[j] = *(const bf16x8*)&Bs[row * 32 + ((g ^ ((row >> 1) & 3)) << 3)];
        }
#pragma unroll
        for (int i = 0; i < 4; i++)
#pragma unroll
            for (int j = 0; j < 4; j++)
                acc[i][j] = __builtin_amdgcn_mfma_f32_16x16x32_bf16(av[i], bv[j], acc[i][j], 0, 0, 0);
    }

    const float scl = (MODE == 1 && mat == 0) ? QSCALE : 1.0f;
#pragma unroll
    for (int j = 0; j < 4; j++) {
        const int   nl   = wc * 64 + j * 16 + c;
        const int   n    = n0 + nl;
        const float bval = Bi[n];
#pragma unroll
        for (int i = 0; i < 4; i++) {
#pragma unroll
            for (int r = 0; r < 4; r++) {
                const size_t m   = m0 + wr * 64 + i * 16 + g * 4 + r;
                const float  val = (acc[i][j][r] + bval) * scl;
                if (MODE == 0) {
                    ((float*)O0v)[m * 1024 + n] = val;
                } else {
                    const bf16 ob = (bf16)val;
                    const int  bb = (int)(m >> 11), s = (int)(m & 2047);
                    const int  hh = n >> 6, d = n & 63;
                    if (mat < 2) {
                        bf16* Oqk = (mat == 0) ? (bf16*)O0v : (bf16*)O1v;
                        Oqk[(((size_t)bb * 16 + hh) * 2048 + s) * 64 + d] = ob;
                    } else {
                        ((bf16*)O2v)[(((size_t)bb * 16 + hh) * 64 + d) * 2048 + s] = ob;  // vT
                    }
                }
            }
        }
    }
}

// ---------------------------------------------------------------------------
// GEMM n64: BM=128, BN=64 — OUT-PROJ (512 blocks = 2/CU).  (unchanged)
// ---------------------------------------------------------------------------
template<int MODE>
__global__ __launch_bounds__(256)
void gemm_n64(const bf16* __restrict__ A0, const bf16* __restrict__ W0,
              const float* __restrict__ B0, void* __restrict__ O0v)
{
    __shared__ __align__(16) bf16 As[128 * 32];
    __shared__ __align__(16) bf16 Bs[64 * 32];

    const int tid  = threadIdx.x;
    const int lane = tid & 63;
    const int w    = tid >> 6;
    const int wr   = w >> 1, wc = w & 1;
    const int g    = lane >> 4, c = lane & 15;

    const int mb = blockIdx.x, nbi = blockIdx.y;

    const size_t m0 = (size_t)mb * 128;
    const int    n0 = nbi * 64;

    f32x4 acc[4][2];
#pragma unroll
    for (int i = 0; i < 4; i++)
#pragma unroll
        for (int j = 0; j < 2; j++) acc[i][j] = (f32x4){0.f, 0.f, 0.f, 0.f};

    const int srow = lane >> 2;
    const int spos = lane & 3;

    for (int k0 = 0; k0 < 1024; k0 += 32) {
        __syncthreads();
#pragma unroll
        for (int s = 0; s < 2; s++) {
            const int ca  = w * 2 + s;
            const int row = ca * 16 + srow;
            GLDS16(A0 + (size_t)(m0 + row) * 1024 + k0 + ((spos ^ ((row >> 1) & 3)) << 3),
                   &As[ca * 512]);
        }
        {
            const int row = w * 16 + srow;
            GLDS16(W0 + (size_t)(n0 + row) * 1024 + k0 + ((spos ^ ((row >> 1) & 3)) << 3),
                   &Bs[w * 512]);
        }
        __syncthreads();

        bf16x8 av[4], bv[2];
#pragma unroll
        for (int i = 0; i < 4; i++) {
            const int row = wr * 64 + i * 16 + c;
            av[i] = *(const bf16x8*)&As[row * 32 + ((g ^ ((row >> 1) & 3)) << 3)];
        }
#pragma unroll
        for (int j = 0; j < 2; j++) {
            const int row = wc * 32 + j * 16 + c;
            bv[j] = *(const bf16x8*)&Bs[row * 32 + ((g ^ ((row >> 1) & 3)) << 3)];
        }
#pragma unroll
        for (int i = 0; i < 4; i++)
#pragma unroll
            for (int j = 0; j < 2; j++)
                acc[i][j] = __builtin_amdgcn_mfma_f32_16x16x32_bf16(av[i], bv[j], acc[i][j], 0, 0, 0);
    }

#pragma unroll
    for (int j = 0; j < 2; j++) {
        const int   nl   = wc * 32 + j * 16 + c;
        const int   n    = n0 + nl;
        const float bval = B0[n];
#pragma unroll
        for (int i = 0; i < 4; i++) {
#pragma unroll
            for (int r = 0; r < 4; r++) {
                const size_t m = m0 + wr * 64 + i * 16 + g * 4 + r;
                ((float*)O0v)[m * 1024 + n] = acc[i][j][r] + bval;
            }
        }
    }
}

// ---------------------------------------------------------------------------
// Fallback GEMM (fp32 staging) — used only if ws_size < 64 MB.  (unchanged)
// ---------------------------------------------------------------------------
template<int MODE>
__global__ __launch_bounds__(256)
void gemm_bt(const void* __restrict__ A0v, const void* __restrict__ A1v, const void* __restrict__ A2v,
             const float* __restrict__ W0, const float* __restrict__ W1, const float* __restrict__ W2,
             const float* __restrict__ B0, const float* __restrict__ B1, const float* __restrict__ B2,
             void* __restrict__ O0v, void* __restrict__ O1v, void* __restrict__ O2v)
{
    __shared__ __align__(16) float AsF[128 * 32];
    __shared__ __align__(16) float BsF[128 * 32];
    bf16* AsH = (bf16*)AsF;

    const int tid  = threadIdx.x;
    const int lane = tid & 63;
    const int w    = tid >> 6;
    const int wr   = w >> 1, wc = w & 1;
    const int g    = lane >> 4, c = lane & 15;

    const int mb  = blockIdx.x, nb = blockIdx.y;
    const int mat = (MODE == 1) ? (nb >> 3) : 0;
    const int nbi = (MODE == 1) ? (nb & 7) : nb;

    const float* Af = (MODE == 1)
        ? (mat == 0 ? (const float*)A0v : (mat == 1 ? (const float*)A1v : (const float*)A2v))
        : nullptr;
    const bf16*  Ah = (MODE == 0) ? (const bf16*)A0v : nullptr;
    const float* W  = (MODE == 1) ? (mat == 0 ? W0 : (mat == 1 ? W1 : W2)) : W0;
    const float* Bi = (MODE == 1) ? (mat == 0 ? B0 : (mat == 1 ? B1 : B2)) : B0;

    const size_t m0 = (size_t)mb * 128;
    const int    n0 = nbi * 128;

    f32x4 acc[4][4];
#pragma unroll
    for (int i = 0; i < 4; i++)
#pragma unroll
        for (int j = 0; j < 4; j++) acc[i][j] = (f32x4){0.f, 0.f, 0.f, 0.f};

    for (int k0 = 0; k0 < 1024; k0 += 32) {
        __syncthreads();
        if constexpr (MODE == 1) {
#pragma unroll
            for (int s = 0; s < 4; s++) {
                const int ca  = w * 4 + s;
                const int row = ca * 8 + (lane >> 3);
                const int pos = lane & 7;
                GLDS16(Af + (size_t)(m0 + row) * 1024 + k0 + ((pos ^ (row & 7)) << 2), &AsF[ca * 256]);
            }
        } else {
#pragma unroll
            for (int s = 0; s < 2; s++) {
                const int ca  = w * 2 + s;
                const int row = ca * 16 + (lane >> 2);
                const int pos = lane & 3;
                GLDS16(Ah + (size_t)(m0 + row) * 1024 + k0 + ((pos ^ ((row >> 1) & 3)) << 3), &AsH[ca * 512]);
            }
        }
#pragma unroll
        for (int s = 0; s < 4; s++) {
            const int cb  = w * 4 + s;
            const int row = cb * 8 + (lane >> 3);
            const int pos = lane & 7;
            GLDS16(W + (size_t)(n0 + row) * 1024 + k0 + ((pos ^ (row & 7)) << 2), &BsF[cb * 256]);
        }
        __syncthreads();

        bf16x8 av[4], bv[4];
#pragma unroll
        for (int i = 0; i < 4; i++) {
            const int row = wr * 64 + i * 16 + c;
            if constexpr (MODE == 1) {
                const int s7 = row & 7;
                const f32x4 lo = *(const f32x4*)&AsF[row * 32 + (((2 * g)     ^ s7) << 2)];
                const f32x4 hi = *(const f32x4*)&AsF[row * 32 + (((2 * g + 1) ^ s7) << 2)];
                av[i] = cvt8(lo, hi);
            } else {
                av[i] = *(const bf16x8*)&AsH[row * 32 + ((g ^ ((row >> 1) & 3)) << 3)];
            }
        }
#pragma unroll
        for (int j = 0; j < 4; j++) {
            const int row = wc * 64 + j * 16 + c;
            const int s7  = row & 7;
            const f32x4 lo = *(const f32x4*)&BsF[row * 32 + (((2 * g)     ^ s7) << 2)];
            const f32x4 hi = *(const f32x4*)&BsF[row * 32 + (((2 * g + 1) ^ s7) << 2)];
            bv[j] = cvt8(lo, hi);
        }
#pragma unroll
        for (int i = 0; i < 4; i++)
#pragma unroll
            for (int j = 0; j < 4; j++)
                acc[i][j] = __builtin_amdgcn_mfma_f32_16x16x32_bf16(av[i], bv[j], acc[i][j], 0, 0, 0);
    }

    const float scl = (MODE == 1 && mat == 0) ? QSCALE : 1.0f;
#pragma unroll
    for (int j = 0; j < 4; j++) {
        const int   nl   = wc * 64 + j * 16 + c;
        const int   n    = n0 + nl;
        const float bval = Bi[n];
#pragma unroll
        for (int i = 0; i < 4; i++) {
#pragma unroll
            for (int r = 0; r < 4; r++) {
                const size_t m   = m0 + wr * 64 + i * 16 + g * 4 + r;
                const float  val = (acc[i][j][r] + bval) * scl;
                if (MODE == 0) {
                    ((float*)O0v)[m * 1024 + n] = val;
                } else {
                    const bf16 ob = (bf16)val;
                    const int  bb = (int)(m >> 11), s = (int)(m & 2047);
                    const int  hh = n >> 6, d = n & 63;
                    if (mat < 2) {
                        bf16* Oqk = (mat == 0) ? (bf16*)O0v : (bf16*)O1v;
                        Oqk[(((size_t)bb * 16 + hh) * 2048 + s) * 64 + d] = ob;
                    } else {
                        ((bf16*)O2v)[(((size_t)bb * 16 + hh) * 64 + d) * 2048 + s] = ob;  // vT
                    }
                }
            }
        }
    }
}

// ---------------------------------------------------------------------------
// Attention v7: QBLK=64 (R6 geometry) with 32 KB LDS -> 5 blocks/CU.
// LDS union SM[16384] bf16:
//   pass A: K dbuf = SM[0..8192)
//   pass B: K single = SM[0..4096), V dbuf = SM[4096..12288), Ps = SM[12288..16384)
// Pass B per tile: issue V(t+1) [dbuf] -> QK^T(Ks) -> barrier -> issue K(t+1)
// into Ks -> softmax + nt P-stores + Ps -> PV -> vmcnt(16) -> barrier.
// ---------------------------------------------------------------------------
__global__ __launch_bounds__(256, 5)
void attn_kernel(const bf16* __restrict__ Qh, const bf16* __restrict__ Kh,
                 const bf16* __restrict__ VhT, float* __restrict__ PW,
                 bf16* __restrict__ AO)
{
    __shared__ __align__(16) bf16 SM[16384];   // 32 KB

    const int tid  = threadIdx.x;
    const int lane = tid & 63;
    const int w    = tid >> 6;
    const int g    = lane >> 4, c = lane & 15;

    const int L   = blockIdx.x;                 // 0..1023
    const int swz = (L & 7) * 128 + (L >> 3);
    const int bh  = swz >> 5;
    const int qb  = swz & 31;

    const bf16* qp = Qh + (((size_t)bh * 2048) + qb * 64) * 64;
    const bf16* kp = Kh + ((size_t)bh * 2048) * 64;
    const bf16* vp = VhT + ((size_t)bh * 64) * 2048;
    float*      pw = PW + (size_t)bh * 2048 * 2048 + (size_t)(qb * 64) * 2048;

    bf16x8 aq[2];
#pragma unroll
    for (int kk = 0; kk < 2; kk++)
        aq[kk] = *(const bf16x8*)(qp + (w * 16 + c) * 64 + kk * 32 + g * 8);

    const int srow = (lane >> 3);
    const int spos = lane & 7;

    // ---- PASS A: K dbuf in SM[0..8192), per-lane partial sums of exp2 ----
    float lr[4] = {0.f, 0.f, 0.f, 0.f};
#pragma unroll
    for (int s2 = 0; s2 < 2; s2++) {
        const int cs = w * 2 + s2, row = cs * 8 + srow;
        GLDS16(kp + (size_t)row * 64 + ((spos ^ (row & 7)) << 3), &SM[cs * 512]);
    }
    asm volatile("s_waitcnt vmcnt(0)" ::: "memory");
    __builtin_amdgcn_s_barrier();
    asm volatile("" ::: "memory");

    for (int t = 0; t < 32; t++) {
        const bf16* kb = &SM[(t & 1) * 4096];
        if (t < 31) {
#pragma unroll
            for (int s2 = 0; s2 < 2; s2++) {
                const int cs = w * 2 + s2, row = cs * 8 + srow;
                GLDS16(kp + (size_t)((t + 1) * 64 + row) * 64 + ((spos ^ (row & 7)) << 3),
                       &SM[((t + 1) & 1) * 4096 + cs * 512]);
            }
        }
        f32x4 sj[4];
#pragma unroll
        for (int j = 0; j < 4; j++) sj[j] = (f32x4){0.f, 0.f, 0.f, 0.f};
#pragma unroll
        for (int kk = 0; kk < 2; kk++) {
#pragma unroll
            for (int j = 0; j < 4; j++) {
                const int row = j * 16 + c;
                const bf16x8 bk = *(const bf16x8*)&kb[row * 64 + (((kk * 4 + g) ^ (row & 7)) << 3)];
                sj[j] = __builtin_amdgcn_mfma_f32_16x16x32_bf16(aq[kk], bk, sj[j], 0, 0, 0);
            }
        }
#pragma unroll
        for (int r = 0; r < 4; r++)
            lr[r] += exp2f(sj[0][r]) + exp2f(sj[1][r]) + exp2f(sj[2][r]) + exp2f(sj[3][r]);

        asm volatile("s_waitcnt vmcnt(0)" ::: "memory");
        __builtin_amdgcn_s_barrier();
        asm volatile("" ::: "memory");
    }

    float inv[4];
#pragma unroll
    for (int r = 0; r < 4; r++) {
        float s = lr[r];
        s += __shfl_xor(s, 1);
        s += __shfl_xor(s, 2);
        s += __shfl_xor(s, 4);
        s += __shfl_xor(s, 8);
        inv[r] = 1.0f / s;
    }

    f32x4 oj[4];
#pragma unroll
    for (int j = 0; j < 4; j++) oj[j] = (f32x4){0.f, 0.f, 0.f, 0.f};

    // ---- PASS B: K single buf SM[0..4096), V dbuf SM[4096..12288), Ps SM[12288..) ----
    bf16* Ks = SM;
    bf16* Vs = SM + 4096;
    bf16* Ps = SM + 12288;

#pragma unroll
    for (int s2 = 0; s2 < 2; s2++) {            // stage K(0), V(0)->Vs buf0
        const int cs = w * 2 + s2, row = cs * 8 + srow;
        GLDS16(kp + (size_t)row * 64 + ((spos ^ (row & 7)) << 3), &Ks[cs * 512]);
        GLDS16(vp + (size_t)row * 2048 + ((spos ^ (row & 7)) << 3), &Vs[cs * 512]);
    }
    asm volatile("s_waitcnt vmcnt(0)" ::: "memory");
    __builtin_amdgcn_s_barrier();
    asm volatile("" ::: "memory");

    for (int t = 0; t < 32; t++) {
        const bf16* vb = &Vs[(t & 1) * 4096];
        if (t < 31) {                            // V(t+1) -> other V buf (dbuf: safe now)
#pragma unroll
            for (int s2 = 0; s2 < 2; s2++) {
                const int cs = w * 2 + s2, row = cs * 8 + srow;
                GLDS16(vp + (size_t)row * 2048 + (t + 1) * 64 + ((spos ^ (row & 7)) << 3),
                       &Vs[((t + 1) & 1) * 4096 + cs * 512]);
            }
        }
        // QK^T from single-buffered Ks
        f32x4 sj[4];
#pragma unroll
        for (int j = 0; j < 4; j++) sj[j] = (f32x4){0.f, 0.f, 0.f, 0.f};
#pragma unroll
        for (int kk = 0; kk < 2; kk++) {
#pragma unroll
            for (int j = 0; j < 4; j++) {
                const int row = j * 16 + c;
                const bf16x8 bk = *(const bf16x8*)&Ks[row * 64 + (((kk * 4 + g) ^ (row & 7)) << 3)];
                sj[j] = __builtin_amdgcn_mfma_f32_16x16x32_bf16(aq[kk], bk, sj[j], 0, 0, 0);
            }
        }
        // all waves done reading Ks -> safe to overwrite
        __builtin_amdgcn_s_barrier();
        asm volatile("" ::: "memory");
        if (t < 31) {                            // K(t+1) -> Ks
#pragma unroll
            for (int s2 = 0; s2 < 2; s2++) {
                const int cs = w * 2 + s2, row = cs * 8 + srow;
                GLDS16(kp + (size_t)((t + 1) * 64 + row) * 64 + ((spos ^ (row & 7)) << 3),
                       &Ks[cs * 512]);
            }
        }
        // normalized P: fp32 nontemporal from regs + bf16 to wave-private Ps
#pragma unroll
        for (int j = 0; j < 4; j++) {
#pragma unroll
            for (int r = 0; r < 4; r++) {
                const float p   = exp2f(sj[j][r]) * inv[r];
                const int   row = w * 16 + g * 4 + r;
                const int   col = j * 16 + c;
                __builtin_nontemporal_store(p, &pw[(size_t)row * 2048 + t * 64 + col]);
                Ps[row * 64 + (((col >> 3) ^ (row & 7)) << 3) + (col & 7)] = (bf16)p;
            }
        }
        // O += P V  (Ps rows are this wave's own band: no barrier needed)
#pragma unroll
        for (int kk = 0; kk < 2; kk++) {
            const int prow = w * 16 + c;
            const bf16x8 ap = *(const bf16x8*)&Ps[prow * 64 + (((kk * 4 + g) ^ (prow & 7)) << 3)];
#pragma unroll
            for (int j = 0; j < 4; j++) {
                const int vrow = j * 16 + c;
                const bf16x8 bvv = *(const bf16x8*)&vb[vrow * 64 + (((kk * 4 + g) ^ (vrow & 7)) << 3)];
                oj[j] = __builtin_amdgcn_mfma_f32_16x16x32_bf16(ap, bvv, oj[j], 0, 0, 0);
            }
        }
        // drain this tile's 4 K/V loads (oldest after prev-tile stores); 16 P-stores stay
        asm volatile("s_waitcnt vmcnt(16)" ::: "memory");
        __builtin_amdgcn_s_barrier();
        asm volatile("" ::: "memory");
    }

    const int b = bh >> 4, h = bh & 15;
#pragma unroll
    for (int j = 0; j < 4; j++) {
#pragma unroll
        for (int r = 0; r < 4; r++) {
            const size_t m = (size_t)b * 2048 + qb * 64 + w * 16 + g * 4 + r;
            const int    n = h * 64 + j * 16 + c;
            AO[m * 1024 + n] = (bf16)oj[j][r];
        }
    }
}

// ---------------------------------------------------------------------------
extern "C" void kernel_launch(void* const* d_in, const int* in_sizes, int n_in,
                              void* d_out, int out_size, void* d_ws, size_t ws_size,
                              hipStream_t stream)
{
    const float* Q  = (const float*)d_in[0];
    const float* K  = (const float*)d_in[1];
    const float* V  = (const float*)d_in[2];
    const float* Wq = (const float*)d_in[3];
    const float* bq = (const float*)d_in[4];
    const float* Wk = (const float*)d_in[5];
    const float* bk = (const float*)d_in[6];
    const float* Wv = (const float*)d_in[7];
    const float* bv = (const float*)d_in[8];
    const float* Wo = (const float*)d_in[9];
    const float* bo = (const float*)d_in[10];

    float* outf  = (float*)d_out;                        // [4096][1024] f32
    float* attnw = outf + (size_t)4096 * 1024;           // [32][2048][2048] f32

    bf16* ws   = (bf16*)d_ws;
    bf16* qws  = ws;                                     // [32][2048][64] (pre-scaled)
    bf16* kws  = ws + 4194304;                           // [32][2048][64]
    bf16* vws  = ws + 8388608;                           // [32][64][2048] (transposed)
    bf16* aows = ws + 12582912;                          // [4096][1024]

    if (ws_size >= 67108864) {
        bf16* Qb  = ws + 16777216;
        bf16* Kb  = ws + 20971520;
        bf16* Vb  = ws + 25165824;
        bf16* Wqb = ws + 29360128;
        bf16* Wkb = ws + 30408704;
        bf16* Wvb = ws + 31457280;
        bf16* Wob = ws + 32505856;

        cvt7<<<dim3(2048, 7), 256, 0, stream>>>(Q, K, V, Wq, Wk, Wv, Wo,
                                                Qb, Kb, Vb, Wqb, Wkb, Wvb, Wob);
        gemm_bb<1><<<dim3(32, 24), 256, 0, stream>>>(Qb, Kb, Vb, Wqb, Wkb, Wvb,
                                                     bq, bk, bv, qws, kws, vws);
        attn_kernel<<<dim3(1024), 256, 0, stream>>>(qws, kws, vws, attnw, aows);
        gemm_n64<0><<<dim3(32, 16), 256, 0, stream>>>(aows, Wob, bo, outf);
    } else {
        gemm_bt<1><<<dim3(32, 24), 256, 0, stream>>>(Q, K, V, Wq, Wk, Wv, bq, bk, bv, qws, kws, vws);
        attn_kernel<<<dim3(1024), 256, 0, stream>>>(qws, kws, vws, attnw, aows);
        gemm_bt<0><<<dim3(32, 8), 256, 0, stream>>>(aows, nullptr, nullptr, Wo, nullptr, nullptr,
                                                    bo, nullptr, nullptr, outf, nullptr, nullptr);
    }
}